// Round 5
// baseline (181.608 us; speedup 1.0000x reference)
//
#include <hip/hip_runtime.h>
#include <stdint.h>

#define BB    2048
#define DIN   4096
#define DOUT  4096

// ---------------------------------------------------------------------------
// i8 MFMA bit-GEMM. x,m -> ±1 int8; dot± = 2*sums - 4096;
// out = sums > thr  <=>  dot± > 2*thr - 4096. Exact in i32. (R7: absmax 0)
// ws: x8 ±1 [BB][DIN] @0 (8 MB); m8T ±1 [DOUT][DIN] @8MB (16 MB).
//
// R12 post-mortem: phase-split + 2 barriers/phase regressed again (54us).
// Evidence across R8/R9/R11/R12: every added barrier rendezvous costs more
// than the rotation it buys; within-block waves reconverge at each barrier
// so read-burst/MFMA-burst alternation stands (wall~sum). R8's real second
// lever was 2 INDEPENDENT blocks/CU whose barriers interleave freely.
// R13: combine the two proven levers, never both before: R8 schedule
// (1 __syncthreads/chunk, dbuf) + R11 ratio (wave 128x64, split-K) at
// 128x128 block/64KB LDS -> 2 blocks/CU; setprio around MFMA (cross-block
// arbitration = the regime where it pays). pack_all transpose branch:
// LDS-staged (16B/lane reads, v_perm 4x4, [64][68] u32, ds_read_b128
// columns, 16B/lane stores in 64B runs) -> 4x bigger transactions.
// ---------------------------------------------------------------------------

using v4i  = __attribute__((ext_vector_type(4)))  int;
using v16i = __attribute__((ext_vector_type(16))) int;

__device__ __forceinline__ void async_load16(const void* g, void* l) {
    __builtin_amdgcn_global_load_lds(
        (const __attribute__((address_space(1))) unsigned int*)g,
        (__attribute__((address_space(3))) unsigned int*)l,
        16, 0, 0);
}

// bytes {0,1} -> {+1, -1(0xFF)}; no cross-byte carries.
__device__ __forceinline__ unsigned int to_pm1(unsigned int c) {
    return c + ((c ^ 0x01010101u) * 255u);
}

// Fused packing.
// blocks [0,BB): x int32 {0,1} row -> x8 ±1 bytes (R0 structure, proven).
// blocks [BB, BB+1024): 64(n) x 256(k) LDS-staged transpose of masks.
__global__ void pack_all(const int* __restrict__ x,
                         const void* __restrict__ mraw,
                         char* __restrict__ x8,
                         char* __restrict__ m8T) {
    const int tid = threadIdx.x;
    if (blockIdx.x < BB) {
        const int row = blockIdx.x;
        const int4* src = (const int4*)(x + (size_t)row * DIN);
        unsigned int* dst = (unsigned int*)(x8 + (size_t)row * DIN);
        #pragma unroll
        for (int q = 0; q < 4; ++q) {
            int4 v = src[q * 256 + tid];           // coalesced 16B/lane
            unsigned int t = (unsigned int)(v.x & 1) |
                             ((unsigned int)(v.y & 1) << 8) |
                             ((unsigned int)(v.z & 1) << 16) |
                             ((unsigned int)(v.w & 1) << 24);
            dst[q * 256 + tid] = to_pm1(t);        // coalesced 4B/lane
        }
    } else {
        const int bw = blockIdx.x - BB;            // 0..1023
        const int n0 = (bw >> 4) * 64;             // 64 n-tiles
        const int k0 = (bw & 15) * 256;            // 16 k-strips of 256

        __shared__ unsigned int tl[64][68];        // [n][k-word], pad 68

        // dtype detect (u8-bool vs int32), exact: int32 words are {0,1};
        // u8-bool words exceed 1 unless bytes 1-3 all zero (P ~ 8^-64/wave).
        const unsigned char* mb = (const unsigned char*)mraw;
        const unsigned int pv = *(const unsigned int*)(mb + (tid & 63) * 4);
        const bool isU8 = __any(pv > 1u);

        // stage 1: thread reads 4 k-rows x 16 n-cols (16B/lane coalesced;
        // per instr 16 rows x 64B transactions).
        const int kq4  = tid >> 2;                 // 0..63: k-quad index
        const int nq16 = (tid & 3) * 16;           // n-group base
        unsigned int b[4][4];                      // [k-row r][n-word w]
        if (isU8) {
            #pragma unroll
            for (int r = 0; r < 4; ++r) {
                uint4 v = *(const uint4*)(mb + (size_t)(k0 + kq4 * 4 + r) * DOUT
                                          + n0 + nq16);
                b[r][0] = v.x; b[r][1] = v.y; b[r][2] = v.z; b[r][3] = v.w;
            }
        } else {
            const int4* m32 = (const int4*)mraw;
            #pragma unroll
            for (int r = 0; r < 4; ++r)
                #pragma unroll
                for (int q = 0; q < 4; ++q) {
                    int4 v = m32[((size_t)(k0 + kq4 * 4 + r) * DOUT
                                  + n0 + nq16 + q * 4) >> 2];
                    b[r][q] = (unsigned int)(v.x & 1) |
                              ((unsigned int)(v.y & 1) << 8) |
                              ((unsigned int)(v.z & 1) << 16) |
                              ((unsigned int)(v.w & 1) << 24);
                }
        }
        // transpose each 4x4 byte block via v_perm (verified recipe), ±1,
        // write n-major into LDS: word [n][kq4] = bytes k=k0+kq4*4..+3.
        #pragma unroll
        for (int w = 0; w < 4; ++w) {
            unsigned int a0 = b[0][w], a1 = b[1][w], a2 = b[2][w], a3 = b[3][w];
            unsigned int x0 = __builtin_amdgcn_perm(a1, a0, 0x05010400u);
            unsigned int x1 = __builtin_amdgcn_perm(a3, a2, 0x05010400u);
            unsigned int x2 = __builtin_amdgcn_perm(a1, a0, 0x07030602u);
            unsigned int x3 = __builtin_amdgcn_perm(a3, a2, 0x07030602u);
            unsigned int c0 = __builtin_amdgcn_perm(x1, x0, 0x05040100u);
            unsigned int c1 = __builtin_amdgcn_perm(x1, x0, 0x07060302u);
            unsigned int c2 = __builtin_amdgcn_perm(x3, x2, 0x05040100u);
            unsigned int c3 = __builtin_amdgcn_perm(x3, x2, 0x07060302u);
            tl[nq16 + w * 4 + 0][kq4] = to_pm1(c0);
            tl[nq16 + w * 4 + 1][kq4] = to_pm1(c1);
            tl[nq16 + w * 4 + 2][kq4] = to_pm1(c2);
            tl[nq16 + w * 4 + 3][kq4] = to_pm1(c3);
        }
        __syncthreads();

        // stage 2: thread (nr = t>>2, c4 = t&3) writes 4x16B of row n0+nr;
        // per instr 4 lanes x 16B consecutive = 64B runs. LDS reads b128,
        // banks uniform over quads ((nr*17 + c4 + 4q) mod 8).
        const int nr = tid >> 2;
        const int c4 = tid & 3;
        #pragma unroll
        for (int q = 0; q < 4; ++q) {
            uint4 v = *(const uint4*)&tl[nr][4 * (c4 + 4 * q)];
            *(uint4*)(m8T + (size_t)(n0 + nr) * DIN + k0 + 16 * (c4 + 4 * q)) = v;
        }
    }
}

// i8 MFMA GEMM: 128(m)x128(n) block tile, 4 waves = 2n x 2k(split-K),
// wave tile 128x64 (acc[4][2], reads/MFMA 0.75). BK=128 chunks (32),
// double-buffer LDS (64 KB -> 2 blocks/CU), R8 schedule: one
// __syncthreads per chunk, async global->LDS prefetch of chunk+1.
// setprio(1) around MFMA cluster (cross-block arbitration).
// LDS layout: [row][slot], slot = kgroup ^ (row&7), 8 kgroups x 16 B.
__global__ __launch_bounds__(256)
void bgemm(const char* __restrict__ x8,
           const char* __restrict__ m8T,
           const int* __restrict__ thr,
           int* __restrict__ out) {
    // XCD-aware swizzle: flat%8 = XCD; each XCD a compact 8m x 8n patch.
    const int flat = blockIdx.x;                   // 0..511
    const int xcd  = flat & 7;
    const int idx  = flat >> 3;                    // 0..63
    const int bm   = (xcd & 1) * 8 + (idx & 7);    // 0..15
    const int bn   = (xcd >> 1) * 8 + (idx >> 3);  // 0..31
    const int b0   = bm * 128;                     // m
    const int o0   = bn * 128;                     // n

    const int tid  = threadIdx.x;
    const int lane = tid & 63;
    const int wv   = tid >> 6;           // 0..3
    const int in_  = wv & 1;             // n-half
    const int kh   = wv >> 1;            // split-K half: kgroups kh*4..+3
    const int wn   = in_ * 64;           // wave tile n origin (m origin = 0)
    const int l31  = lane & 31;
    const int lh   = lane >> 5;
    const int rsw  = l31 & 7;            // row&7 term for frag reads

    // buffer b: A (16KB) at b*32768, B (16KB) at b*32768+16384.
    // Pool for split-K combine reuses all 64 KB after the loop.
    __shared__ __align__(16) char lds[65536];

    // stage chunk c -> buf. Per instr: 8 rows x 128 B contiguous LDS (1KB).
    // lane: row = r0 + l/8, slot s = l&7, global kgroup g = s ^ (row&7).
    // 8 global_load_lds per thread per chunk (A:4, B:4).
    auto stage = [&](int c, int buf) {
        char* bufA = lds + buf * 32768;
        char* bufB = bufA + 16384;
        const int k0 = c * 128;
        const int r8 = lane >> 3;
        const int sl = lane & 7;
        #pragma unroll
        for (int h = 0; h < 4; ++h) {
            const int r0  = wv * 32 + h * 8;
            const int row = r0 + r8;
            const int g   = sl ^ (row & 7);
            async_load16(x8 + (size_t)(b0 + row) * DIN + k0 + g * 16,
                         bufA + r0 * 128 + lane * 16);
            async_load16(m8T + (size_t)(o0 + row) * DIN + k0 + g * 16,
                         bufB + r0 * 128 + lane * 16);
        }
    };

    v16i acc[4][2];
    #pragma unroll
    for (int t = 0; t < 4; ++t)
        #pragma unroll
        for (int u = 0; u < 2; ++u)
            acc[t][u] = (v16i)(0);

    stage(0, 0);
    __syncthreads();

    for (int c = 0; c < 32; ++c) {
        const int buf = c & 1;
        if (c < 31) stage(c + 1, buf ^ 1);   // async, overlaps compute

        const char* bufA = lds + buf * 32768;
        const char* bufB = bufA + 16384;
        #pragma unroll
        for (int ks = 0; ks < 2; ++ks) {
            // this wave's kgroups: kh*4 + ks*2 + lh
            const int slot = (((kh * 4 + ks * 2 + lh) ^ rsw)) * 16;
            v4i aF[4], bF[2];
            #pragma unroll
            for (int t = 0; t < 4; ++t)
                aF[t] = *(const v4i*)&bufA[(t * 32 + l31) * 128 + slot];
            #pragma unroll
            for (int u = 0; u < 2; ++u)
                bF[u] = *(const v4i*)&bufB[(wn + u * 32 + l31) * 128 + slot];
            __builtin_amdgcn_s_setprio(1);
            #pragma unroll
            for (int t = 0; t < 4; ++t)
                #pragma unroll
                for (int u = 0; u < 2; ++u)
                    acc[t][u] = __builtin_amdgcn_mfma_i32_32x32x32_i8(
                        aF[t], bF[u], acc[t][u], 0, 0, 0);
            __builtin_amdgcn_s_setprio(0);
        }
        __syncthreads();   // drains chunk+1 loads; releases buf
    }

    // ---- split-K combine. Pair p = in_: waves (in_, kh=0) and (in_, kh=1)
    // computed the same 128x64 tile over disjoint K halves. kh=0 keeps
    // t0,1 (rows 0..63), gives t2,3; kh=1 keeps t2,3, gives t0,1.
    // Pool: per pair 8192 i32 (2 halves x 4096) = 64 KB total.
    int* pool = (int*)lds;
    const int p = in_;
    {
        const int give0 = kh ? 0 : 2;              // first given t
        const int bw_ = p * 8192 + (kh ? 0 : 1) * 4096;
        #pragma unroll
        for (int tt = 0; tt < 2; ++tt) {
            const int t = give0 + tt;
            #pragma unroll
            for (int u = 0; u < 2; ++u)
                #pragma unroll
                for (int r = 0; r < 16; ++r) {
                    const int rowl = (r & 3) + 8 * (r >> 2) + 4 * lh;
                    pool[bw_ + (tt * 32 + rowl) * 64 + u * 32 + l31] = acc[t][u][r];
                }
        }
    }
    __syncthreads();
    const int keep0 = kh ? 2 : 0;
    const int br_ = p * 8192 + kh * 4096;          // partner's gift = my kept rows
    #pragma unroll
    for (int tt = 0; tt < 2; ++tt) {
        const int t = keep0 + tt;
        #pragma unroll
        for (int u = 0; u < 2; ++u)
            #pragma unroll
            for (int r = 0; r < 16; ++r) {
                const int rowl = (r & 3) + 8 * (r >> 2) + 4 * lh;
                acc[t][u][r] += pool[br_ + (tt * 32 + rowl) * 64 + u * 32 + l31];
            }
    }

    // epilogue: out = (dot± > 2*thr - 4096).
    // C/D layout (verified R7): col = lane&31; row = (reg&3)+8*(reg>>2)+4*(lane>>5).
    #pragma unroll
    for (int u = 0; u < 2; ++u) {
        const int o   = o0 + wn + u * 32 + l31;
        const int lim = 2 * thr[o] - DIN;
        #pragma unroll
        for (int tt = 0; tt < 2; ++tt) {
            const int t = keep0 + tt;
            #pragma unroll
            for (int r = 0; r < 16; ++r) {
                const int rowl = (r & 3) + 8 * (r >> 2) + 4 * lh;
                const int b    = b0 + kh * 64 + tt * 32 + rowl;
                out[(size_t)b * DOUT + o] = (acc[t][u][r] > lim) ? 1 : 0;
            }
        }
    }
}

extern "C" void kernel_launch(void* const* d_in, const int* in_sizes, int n_in,
                              void* d_out, int out_size, void* d_ws, size_t ws_size,
                              hipStream_t stream) {
    const int* x          = (const int*)d_in[0];
    const void* masks     = d_in[1];           // bool: u8 or int32 (detected inline)
    const int* thresholds = (const int*)d_in[2];
    int* out              = (int*)d_out;

    char* x8  = (char*)d_ws;                          // 8 MB
    char* m8T = (char*)d_ws + ((size_t)8 << 20);      // 16 MB

    pack_all<<<BB + 1024, 256, 0, stream>>>(x, masks, x8, m8T);
    bgemm<<<512, 256, 0, stream>>>(x8, m8T, thresholds, out);
}

// Round 6
// 173.983 us; speedup vs baseline: 1.0438x; 1.0438x over previous
//
#include <hip/hip_runtime.h>
#include <stdint.h>

#define BB    2048
#define DIN   4096
#define DOUT  4096

// ---------------------------------------------------------------------------
// i8 MFMA bit-GEMM. x,m -> ±1 int8; dot± = 2*sums - 4096;
// out = sums > thr  <=>  dot± > 2*thr - 4096. Exact in i32. (R7: absmax 0)
// ws: x8 ±1 [BB][DIN] @0 (8 MB); m8T ±1 [DOUT][DIN] @8MB (16 MB).
//
// R13 post-mortem: 128x128/512-block bgemm regressed (79us): FETCH 33->49MB
// (per-XCD L2 working set doubled -> panel thrash), occupancy 10% (2-blk/CU
// co-residence never paid, it thrashed). pack_all LDS transpose WON
// (~21us inferred: absent from top-5; total - bgemm - 81us const overhead).
// R14: recombination of measured bests -- bgemm = R11 verbatim (46.8us:
// 256x128, 8 waves 2m x 2n x 2k split-K, BK=128, triple-buffer 144KB,
// depth-2 prefetch, vmcnt(6), ONE barrier/chunk), pack_all = R13 verbatim.
// bgemm structural floor ~47us stands after 5 failed deviations (R9 phase
// split 58, R10 fat-tile-1blk 66, R12 T3/T4/T5 54, R13 2blk/CU 79).
// ---------------------------------------------------------------------------

using v4i  = __attribute__((ext_vector_type(4)))  int;
using v16i = __attribute__((ext_vector_type(16))) int;

__device__ __forceinline__ void async_load16(const void* g, void* l) {
    __builtin_amdgcn_global_load_lds(
        (const __attribute__((address_space(1))) unsigned int*)g,
        (__attribute__((address_space(3))) unsigned int*)l,
        16, 0, 0);
}

// bytes {0,1} -> {+1, -1(0xFF)}; no cross-byte carries.
__device__ __forceinline__ unsigned int to_pm1(unsigned int c) {
    return c + ((c ^ 0x01010101u) * 255u);
}

// Fused packing.
// blocks [0,BB): x int32 {0,1} row -> x8 ±1 bytes (R0 structure, proven).
// blocks [BB, BB+1024): 64(n) x 256(k) LDS-staged transpose of masks.
__global__ void pack_all(const int* __restrict__ x,
                         const void* __restrict__ mraw,
                         char* __restrict__ x8,
                         char* __restrict__ m8T) {
    const int tid = threadIdx.x;
    if (blockIdx.x < BB) {
        const int row = blockIdx.x;
        const int4* src = (const int4*)(x + (size_t)row * DIN);
        unsigned int* dst = (unsigned int*)(x8 + (size_t)row * DIN);
        #pragma unroll
        for (int q = 0; q < 4; ++q) {
            int4 v = src[q * 256 + tid];           // coalesced 16B/lane
            unsigned int t = (unsigned int)(v.x & 1) |
                             ((unsigned int)(v.y & 1) << 8) |
                             ((unsigned int)(v.z & 1) << 16) |
                             ((unsigned int)(v.w & 1) << 24);
            dst[q * 256 + tid] = to_pm1(t);        // coalesced 4B/lane
        }
    } else {
        const int bw = blockIdx.x - BB;            // 0..1023
        const int n0 = (bw >> 4) * 64;             // 64 n-tiles
        const int k0 = (bw & 15) * 256;            // 16 k-strips of 256

        __shared__ unsigned int tl[64][68];        // [n][k-word], pad 68

        // dtype detect (u8-bool vs int32), exact: int32 words are {0,1};
        // u8-bool words exceed 1 unless bytes 1-3 all zero (P ~ 8^-64/wave).
        const unsigned char* mb = (const unsigned char*)mraw;
        const unsigned int pv = *(const unsigned int*)(mb + (tid & 63) * 4);
        const bool isU8 = __any(pv > 1u);

        // stage 1: thread reads 4 k-rows x 16 n-cols (16B/lane coalesced;
        // per instr 16 rows x 64B transactions).
        const int kq4  = tid >> 2;                 // 0..63: k-quad index
        const int nq16 = (tid & 3) * 16;           // n-group base
        unsigned int b[4][4];                      // [k-row r][n-word w]
        if (isU8) {
            #pragma unroll
            for (int r = 0; r < 4; ++r) {
                uint4 v = *(const uint4*)(mb + (size_t)(k0 + kq4 * 4 + r) * DOUT
                                          + n0 + nq16);
                b[r][0] = v.x; b[r][1] = v.y; b[r][2] = v.z; b[r][3] = v.w;
            }
        } else {
            const int4* m32 = (const int4*)mraw;
            #pragma unroll
            for (int r = 0; r < 4; ++r)
                #pragma unroll
                for (int q = 0; q < 4; ++q) {
                    int4 v = m32[((size_t)(k0 + kq4 * 4 + r) * DOUT
                                  + n0 + nq16 + q * 4) >> 2];
                    b[r][q] = (unsigned int)(v.x & 1) |
                              ((unsigned int)(v.y & 1) << 8) |
                              ((unsigned int)(v.z & 1) << 16) |
                              ((unsigned int)(v.w & 1) << 24);
                }
        }
        // transpose each 4x4 byte block via v_perm (verified recipe), ±1,
        // write n-major into LDS: word [n][kq4] = bytes k=k0+kq4*4..+3.
        #pragma unroll
        for (int w = 0; w < 4; ++w) {
            unsigned int a0 = b[0][w], a1 = b[1][w], a2 = b[2][w], a3 = b[3][w];
            unsigned int x0 = __builtin_amdgcn_perm(a1, a0, 0x05010400u);
            unsigned int x1 = __builtin_amdgcn_perm(a3, a2, 0x05010400u);
            unsigned int x2 = __builtin_amdgcn_perm(a1, a0, 0x07030602u);
            unsigned int x3 = __builtin_amdgcn_perm(a3, a2, 0x07030602u);
            unsigned int c0 = __builtin_amdgcn_perm(x1, x0, 0x05040100u);
            unsigned int c1 = __builtin_amdgcn_perm(x1, x0, 0x07060302u);
            unsigned int c2 = __builtin_amdgcn_perm(x3, x2, 0x05040100u);
            unsigned int c3 = __builtin_amdgcn_perm(x3, x2, 0x07060302u);
            tl[nq16 + w * 4 + 0][kq4] = to_pm1(c0);
            tl[nq16 + w * 4 + 1][kq4] = to_pm1(c1);
            tl[nq16 + w * 4 + 2][kq4] = to_pm1(c2);
            tl[nq16 + w * 4 + 3][kq4] = to_pm1(c3);
        }
        __syncthreads();

        // stage 2: thread (nr = t>>2, c4 = t&3) writes 4x16B of row n0+nr;
        // per instr 4 lanes x 16B consecutive = 64B runs. LDS reads b128,
        // banks uniform over quads ((nr*17 + c4 + 4q) mod 8).
        const int nr = tid >> 2;
        const int c4 = tid & 3;
        #pragma unroll
        for (int q = 0; q < 4; ++q) {
            uint4 v = *(const uint4*)&tl[nr][4 * (c4 + 4 * q)];
            *(uint4*)(m8T + (size_t)(n0 + nr) * DIN + k0 + 16 * (c4 + 4 * q)) = v;
        }
    }
}

// i8 MFMA GEMM (R11 verbatim, 46.8us): 256(m)x128(n) block tile, 8 waves =
// 2m x 2n x 2k(split-K), wave tile 128x64 (acc[4][2]). BK=128 chunks (32),
// triple-buffer LDS (144 KB), depth-2 prefetch, one raw s_barrier per chunk
// with counted vmcnt(6). Split-K combine via LDS pool.
// LDS layout: [row][slot], slot = kgroup ^ (row&7), 8 kgroups x 16 B.
__global__ __launch_bounds__(512)
void bgemm(const char* __restrict__ x8,
           const char* __restrict__ m8T,
           const int* __restrict__ thr,
           int* __restrict__ out) {
    // XCD-aware swizzle: flat%8 = XCD; each XCD a compact 4m x 8n patch.
    const int flat = blockIdx.x;                   // 0..255
    const int xcd  = flat & 7;
    const int idx  = flat >> 3;                    // 0..31
    const int bm   = (xcd & 1) * 4 + (idx & 3);    // 0..7
    const int bn   = (xcd >> 1) * 8 + (idx >> 2);  // 0..31
    const int b0   = bm * 256;                     // m
    const int o0   = bn * 128;                     // n

    const int tid  = threadIdx.x;
    const int lane = tid & 63;
    const int wv   = tid >> 6;           // 0..7
    const int im   = wv & 1;
    const int in_  = (wv >> 1) & 1;
    const int kh   = wv >> 2;            // split-K half: kgroups kh*4..kh*4+3
    const int wm   = im * 128;           // wave tile m origin
    const int wn   = in_ * 64;           // wave tile n origin
    const int l31  = lane & 31;
    const int lh   = lane >> 5;
    const int rsw  = l31 & 7;            // row&7 term for frag reads

    // 3 buffers x (A 32KB + B 16KB) = 144 KB; pool reused for split-K combine.
    __shared__ __align__(16) char lds[3 * 49152];

    // stage chunk c -> buf. Per instr: 8 rows x 128 B contiguous LDS (1KB).
    // lane: row = r0 + l/8, slot s = l&7, global kgroup g = s ^ (row&7).
    // 6 global_load_lds per thread per chunk (A:4, B:2).
    auto stage = [&](int c, int buf) {
        char* bufA = lds + buf * 49152;
        char* bufB = bufA + 32768;
        const int k0 = c * 128;
        const int r8 = lane >> 3;
        const int sl = lane & 7;
        #pragma unroll
        for (int h = 0; h < 4; ++h) {              // A: 32 rows/wave
            const int r0  = wv * 32 + h * 8;
            const int row = r0 + r8;
            const int g   = sl ^ (row & 7);
            async_load16(x8 + (size_t)(b0 + row) * DIN + k0 + g * 16,
                         bufA + r0 * 128 + lane * 16);
        }
        #pragma unroll
        for (int h = 0; h < 2; ++h) {              // B: 16 rows/wave
            const int r0  = wv * 16 + h * 8;
            const int row = r0 + r8;
            const int g   = sl ^ (row & 7);
            async_load16(m8T + (size_t)(o0 + row) * DIN + k0 + g * 16,
                         bufB + r0 * 128 + lane * 16);
        }
    };

    v16i acc[4][2];
    #pragma unroll
    for (int t = 0; t < 4; ++t)
        #pragma unroll
        for (int u = 0; u < 2; ++u)
            acc[t][u] = (v16i)(0);

    // prologue: depth-2 prefetch (12 loads/thread in flight).
    stage(0, 0);
    stage(1, 1);

    for (int c = 0; c < 32; ++c) {
        // drain exactly stage(c): leave stage(c+1) (6 loads) in flight.
        if (c < 31) asm volatile("s_waitcnt vmcnt(6)" ::: "memory");
        else        asm volatile("s_waitcnt vmcnt(0)" ::: "memory");
        __builtin_amdgcn_s_barrier();  // stage(c) visible everywhere; all
                                       // waves done computing c-1 -> buf free
        if (c < 30) stage(c + 2, (c + 2) % 3);

        const char* bufA = lds + (c % 3) * 49152;
        const char* bufB = bufA + 32768;
        #pragma unroll
        for (int ks = 0; ks < 2; ++ks) {
            // this wave's kgroups: kh*4 + ks*2 + lh
            const int slot = (((kh * 4 + ks * 2 + lh) ^ rsw)) * 16;
            v4i aF[4], bF[2];
            #pragma unroll
            for (int t = 0; t < 4; ++t)
                aF[t] = *(const v4i*)&bufA[(wm + t * 32 + l31) * 128 + slot];
            #pragma unroll
            for (int u = 0; u < 2; ++u)
                bF[u] = *(const v4i*)&bufB[(wn + u * 32 + l31) * 128 + slot];
            #pragma unroll
            for (int t = 0; t < 4; ++t)
                #pragma unroll
                for (int u = 0; u < 2; ++u)
                    acc[t][u] = __builtin_amdgcn_mfma_i32_32x32x32_i8(
                        aF[t], bF[u], acc[t][u], 0, 0, 0);
        }
    }
    __syncthreads();   // all compute done; lds pool free for combine

    // ---- split-K combine. Pair p = (im,in_): waves (p, kh=0) and (p, kh=1)
    // computed the same 128x64 tile over disjoint K halves. Each wave gives
    // one 64-row half via LDS and keeps the other: h=0 keeps t0,1 gives t2,3;
    // h=1 keeps t2,3 gives t0,1. Pool: per pair 8192 i32 (2 halves x 4096).
    int* pool = (int*)lds;                         // 128 KB used
    const int p = wv & 3;
    {
        const int give0 = kh ? 0 : 2;              // first given t
        const int bw_ = p * 8192 + (kh ? 0 : 1) * 4096;
        #pragma unroll
        for (int tt = 0; tt < 2; ++tt) {
            const int t = give0 + tt;
            #pragma unroll
            for (int u = 0; u < 2; ++u)
                #pragma unroll
                for (int r = 0; r < 16; ++r) {
                    const int rowl = (r & 3) + 8 * (r >> 2) + 4 * lh;
                    pool[bw_ + (tt * 32 + rowl) * 64 + u * 32 + l31] = acc[t][u][r];
                }
        }
    }
    __syncthreads();
    const int keep0 = kh ? 2 : 0;
    const int br_ = p * 8192 + kh * 4096;          // partner's gift = my kept rows
    #pragma unroll
    for (int tt = 0; tt < 2; ++tt) {
        const int t = keep0 + tt;
        #pragma unroll
        for (int u = 0; u < 2; ++u)
            #pragma unroll
            for (int r = 0; r < 16; ++r) {
                const int rowl = (r & 3) + 8 * (r >> 2) + 4 * lh;
                acc[t][u][r] += pool[br_ + (tt * 32 + rowl) * 64 + u * 32 + l31];
            }
    }

    // epilogue: out = (dot± > 2*thr - 4096).
    // C/D layout (verified R7): col = lane&31; row = (reg&3)+8*(reg>>2)+4*(lane>>5).
    #pragma unroll
    for (int u = 0; u < 2; ++u) {
        const int o   = o0 + wn + u * 32 + l31;
        const int lim = 2 * thr[o] - DIN;
        #pragma unroll
        for (int tt = 0; tt < 2; ++tt) {
            const int t = keep0 + tt;
            #pragma unroll
            for (int r = 0; r < 16; ++r) {
                const int rowl = (r & 3) + 8 * (r >> 2) + 4 * lh;
                const int b    = b0 + wm + kh * 64 + tt * 32 + rowl;
                out[(size_t)b * DOUT + o] = (acc[t][u][r] > lim) ? 1 : 0;
            }
        }
    }
}

extern "C" void kernel_launch(void* const* d_in, const int* in_sizes, int n_in,
                              void* d_out, int out_size, void* d_ws, size_t ws_size,
                              hipStream_t stream) {
    const int* x          = (const int*)d_in[0];
    const void* masks     = d_in[1];           // bool: u8 or int32 (detected inline)
    const int* thresholds = (const int*)d_in[2];
    int* out              = (int*)d_out;

    char* x8  = (char*)d_ws;                          // 8 MB
    char* m8T = (char*)d_ws + ((size_t)8 << 20);      // 16 MB

    pack_all<<<BB + 1024, 256, 0, stream>>>(x, masks, x8, m8T);
    bgemm<<<256, 512, 0, stream>>>(x8, m8T, thresholds, out);
}